// Round 1
// baseline (425.748 us; speedup 1.0000x reference)
//
#include <hip/hip_runtime.h>
#include <stdint.h>
#include <math.h>

#define NB 32  // batch

// ---------------- Threefry-2x32-20 (exact JAX semantics) ----------------
__device__ __forceinline__ void tf_block(uint32_t k0, uint32_t k1, uint32_t& x0, uint32_t& x1) {
  uint32_t k2 = 0x1BD11BDAu ^ k0 ^ k1;
  x0 += k0; x1 += k1;
#define TFR(r) { x0 += x1; x1 = (x1 << r) | (x1 >> (32 - r)); x1 ^= x0; }
  TFR(13) TFR(15) TFR(26) TFR(6)
  x0 += k1; x1 += k2 + 1u;
  TFR(17) TFR(29) TFR(16) TFR(24)
  x0 += k2; x1 += k0 + 2u;
  TFR(13) TFR(15) TFR(26) TFR(6)
  x0 += k0; x1 += k1 + 3u;
  TFR(17) TFR(29) TFR(16) TFR(24)
  x0 += k1; x1 += k2 + 4u;
  TFR(13) TFR(15) TFR(26) TFR(6)
  x0 += k2; x1 += k0 + 5u;
#undef TFR
}

// Computes idx0[64], idx1[128]: jax.random.permutation(kt_i, 256)[:lim]
// where ks,kt = split(fold_in(key(42), i)). Also zeroes the 8 accumulators.
__global__ void perm_kernel(int* idx0, int* idx1, float* accs) {
  __shared__ uint32_t sub[2][2];
  __shared__ uint32_t bits[2][256];
  int t = threadIdx.x;
  if (t < 8) accs[t] = 0.0f;
  if (t == 0) {
    for (int i = 0; i < 2; ++i) {
      // fold_in(key(42), i): threefry_2x32(key=(0,42), count=[0,i]) -> x0=[0], x1=[i]
      uint32_t f0 = 0u, f1 = (uint32_t)i;
      tf_block(0u, 42u, f0, f1);
      // split(folded): counts [0,1,2,3] -> blocks (0,2),(1,3); kt = (e02.x1, e13.x1)
      uint32_t a0 = 0u, a1 = 2u; tf_block(f0, f1, a0, a1);
      uint32_t b0 = 1u, b1 = 3u; tf_block(f0, f1, b0, b1);
      uint32_t kt0 = a1, kt1 = b1;
      // inside permutation: key, subkey = split(kt); subkey = (g02.x1, g13.x1)
      uint32_t c0 = 0u, c1 = 2u; tf_block(kt0, kt1, c0, c1);
      uint32_t d0 = 1u, d1 = 3u; tf_block(kt0, kt1, d0, d1);
      sub[i][0] = c1; sub[i][1] = d1;
    }
  }
  __syncthreads();
  if (t < 128) {
    for (int i = 0; i < 2; ++i) {
      uint32_t x0 = (uint32_t)t, x1 = (uint32_t)(t + 128);
      tf_block(sub[i][0], sub[i][1], x0, x1);
      bits[i][t] = x0; bits[i][t + 128] = x1;
    }
  }
  __syncthreads();
  // stable ascending rank (mirrors lax.sort_key_val stable sort)
  for (int i = 0; i < 2; ++i) {
    uint32_t mine = bits[i][t];
    int rank = 0;
    for (int k = 0; k < 256; ++k) {
      uint32_t v = bits[i][k];
      rank += (v < mine) || (v == mine && k < t);
    }
    int lim = (i == 0) ? 64 : 128;
    if (rank < lim) { (i == 0 ? idx0 : idx1)[rank] = t; }
  }
}

// ---------------- main loss: mean over rows of (logsumexp - pred[target]) ----------------
__global__ void main_loss_kernel(const float* __restrict__ pred, const int* __restrict__ target,
                                 float* accs) {
  int b = blockIdx.x, t = threadIdx.x;
  __shared__ float red[256];
  const float* row = pred + b * 1000;
  float m = -INFINITY;
  for (int j = t; j < 1000; j += 256) m = fmaxf(m, row[j]);
  red[t] = m; __syncthreads();
  for (int s = 128; s > 0; s >>= 1) { if (t < s) red[t] = fmaxf(red[t], red[t + s]); __syncthreads(); }
  m = red[0]; __syncthreads();
  float e = 0.f;
  for (int j = t; j < 1000; j += 256) e += expf(row[j] - m);
  red[t] = e; __syncthreads();
  for (int s = 128; s > 0; s >>= 1) { if (t < s) red[t] += red[t + s]; __syncthreads(); }
  if (t == 0) {
    float lse = logf(red[0]) + m;
    atomicAdd(&accs[0], (lse - row[target[b]]) * (1.0f / 32.0f));
  }
}

// ---------------- pass1: per-(b,c) sum of squares (+ SCR MSE for students) ----------------
// teacher plane is 32x32; student HW upsampled by nearest (repeat) with SHIFT (2 or 1).
template<int C, int HW, int LOGW, int SHIFT, bool STUDENT>
__global__ void pass1_kernel(const float* __restrict__ feat, const float* __restrict__ teacher,
                             const int* __restrict__ tidx, float* __restrict__ normsq,
                             float* scr_acc) {
  int bc = blockIdx.x;
  __shared__ float tpl[1024];
  __shared__ float red[256];
  if constexpr (STUDENT) {
    int b = bc / C, c = bc % C;
    int tc = tidx[c];
    const float4* tp = (const float4*)(teacher + ((size_t)b * 256 + tc) * 1024);
    ((float4*)tpl)[threadIdx.x] = tp[threadIdx.x];  // 256 threads x 16B = 4KB
    __syncthreads();
  }
  const float4* plane = (const float4*)(feat + (size_t)bc * HW);
  float ssq = 0.f, scr = 0.f;
  const int N4 = HW / 4;
  for (int p = threadIdx.x; p < N4; p += 256) {
    float4 v = plane[p];
    ssq += v.x * v.x + v.y * v.y + v.z * v.z + v.w * v.w;
    if constexpr (STUDENT) {
      int pix = p * 4;
      int h = pix >> LOGW;
      int w = pix & ((1 << LOGW) - 1);
      int th = h >> SHIFT;
      if constexpr (SHIFT == 2) {
        float tv = tpl[th * 32 + (w >> 2)];
        float dx = v.x - tv, dy = v.y - tv, dz = v.z - tv, dw = v.w - tv;
        scr += dx * dx + dy * dy + dz * dz + dw * dw;
      } else {
        int tw = w >> 1;
        float t0 = tpl[th * 32 + tw], t1 = tpl[th * 32 + tw + 1];
        float dx = v.x - t0, dy = v.y - t0, dz = v.z - t1, dw = v.w - t1;
        scr += dx * dx + dy * dy + dz * dz + dw * dw;
      }
    }
  }
  red[threadIdx.x] = ssq; __syncthreads();
  for (int s = 128; s > 0; s >>= 1) { if (threadIdx.x < s) red[threadIdx.x] += red[threadIdx.x + s]; __syncthreads(); }
  if (threadIdx.x == 0) normsq[bc] = red[0];
  if constexpr (STUDENT) {
    __syncthreads();
    red[threadIdx.x] = scr; __syncthreads();
    for (int s = 128; s > 0; s >>= 1) { if (threadIdx.x < s) red[threadIdx.x] += red[threadIdx.x + s]; __syncthreads(); }
    if (threadIdx.x == 0) atomicAdd(scr_acc, red[0]);
  }
}

// ---------------- rank: stable descending by sqrt(ssq), strong = rank < C/2 ----------------
template<int C>
__global__ void rank_kernel(const float* __restrict__ normsq, float* __restrict__ flags) {
  int b = blockIdx.x;
  __shared__ float nm[C];
  for (int c = threadIdx.x; c < C; c += 256) nm[c] = sqrtf(normsq[b * C + c]);
  __syncthreads();
  for (int c = threadIdx.x; c < C; c += 256) {
    float mine = nm[c];
    int rank = 0;
    for (int k = 0; k < C; ++k) {
      float v = nm[k];
      rank += (v > mine) || (v == mine && k < c);
    }
    flags[b * C + c] = (rank < C / 2) ? 1.0f : 0.0f;
  }
}

__device__ __forceinline__ float sigmoidf(float x) { return 1.0f / (1.0f + expf(-x)); }

// ---------------- pass2 (float4, 1024 px/block): feat0 ----------------
template<int C, int HW>
__global__ void pass2_vec4(const float* __restrict__ feat, const float* __restrict__ flags,
                           float* ifd_acc, float inv_half) {
  const int nchunk = HW / 1024;
  int b = blockIdx.x / nchunk;
  int chunk = blockIdx.x % nchunk;
  __shared__ float fl[C];
  __shared__ float red[256];
  for (int c = threadIdx.x; c < C; c += 256) fl[c] = flags[b * C + c];
  __syncthreads();
  const float* base = feat + (size_t)b * C * HW + (size_t)chunk * 1024;
  float4 tot = {0, 0, 0, 0}, str = {0, 0, 0, 0};
  for (int c = 0; c < C; ++c) {
    float4 v = ((const float4*)(base + (size_t)c * HW))[threadIdx.x];
    float f = fl[c];
    tot.x += v.x; tot.y += v.y; tot.z += v.z; tot.w += v.w;
    str.x = fmaf(v.x, f, str.x); str.y = fmaf(v.y, f, str.y);
    str.z = fmaf(v.z, f, str.z); str.w = fmaf(v.w, f, str.w);
  }
  float s = 0.f;
  {
    float d;
    d = sigmoidf((tot.x - str.x) * inv_half) - sigmoidf(str.x * inv_half); s += d * d;
    d = sigmoidf((tot.y - str.y) * inv_half) - sigmoidf(str.y * inv_half); s += d * d;
    d = sigmoidf((tot.z - str.z) * inv_half) - sigmoidf(str.z * inv_half); s += d * d;
    d = sigmoidf((tot.w - str.w) * inv_half) - sigmoidf(str.w * inv_half); s += d * d;
  }
  red[threadIdx.x] = s; __syncthreads();
  for (int st = 128; st > 0; st >>= 1) { if (threadIdx.x < st) red[threadIdx.x] += red[threadIdx.x + st]; __syncthreads(); }
  if (threadIdx.x == 0) atomicAdd(ifd_acc, red[0]);
}

// ---------------- pass2 (scalar, 256 px/block): feat1 ----------------
template<int C, int HW>
__global__ void pass2_scalar(const float* __restrict__ feat, const float* __restrict__ flags,
                             float* ifd_acc, float inv_half) {
  const int nchunk = HW / 256;
  int b = blockIdx.x / nchunk;
  int chunk = blockIdx.x % nchunk;
  __shared__ float fl[C];
  __shared__ float red[256];
  for (int c = threadIdx.x; c < C; c += 256) fl[c] = flags[b * C + c];
  __syncthreads();
  const float* base = feat + (size_t)b * C * HW + (size_t)chunk * 256 + threadIdx.x;
  float tot = 0.f, str = 0.f;
  for (int c = 0; c < C; ++c) {
    float v = base[(size_t)c * HW];
    tot += v; str = fmaf(v, fl[c], str);
  }
  float d = sigmoidf((tot - str) * inv_half) - sigmoidf(str * inv_half);
  red[threadIdx.x] = d * d; __syncthreads();
  for (int st = 128; st > 0; st >>= 1) { if (threadIdx.x < st) red[threadIdx.x] += red[threadIdx.x + st]; __syncthreads(); }
  if (threadIdx.x == 0) atomicAdd(ifd_acc, red[0]);
}

// ---------------- pass2 feat2: block per (b, h-row), 8 channel-lanes x 32 px ----------------
__global__ void pass2_feat2(const float* __restrict__ feat, const float* __restrict__ flags,
                            float* ifd_acc) {
  int b = blockIdx.x >> 5;
  int h = blockIdx.x & 31;
  __shared__ float fl[256];
  __shared__ float stot[256], sstr[256];
  fl[threadIdx.x] = flags[b * 256 + threadIdx.x];
  __syncthreads();
  int w = threadIdx.x & 31;
  int cl = threadIdx.x >> 5;  // 0..7
  const float* base = feat + (size_t)b * 256 * 1024 + h * 32 + w;
  float tot = 0.f, str = 0.f;
  for (int cg = 0; cg < 32; ++cg) {
    int c = cg * 8 + cl;
    float v = base[(size_t)c * 1024];
    tot += v; str = fmaf(v, fl[c], str);
  }
  stot[threadIdx.x] = tot; sstr[threadIdx.x] = str;
  __syncthreads();
  float s = 0.f;
  if (threadIdx.x < 32) {
    float T = 0.f, S = 0.f;
    for (int k = 0; k < 8; ++k) { T += stot[k * 32 + threadIdx.x]; S += sstr[k * 32 + threadIdx.x]; }
    const float inv_half = 1.0f / 128.0f;
    float d = sigmoidf((T - S) * inv_half) - sigmoidf(S * inv_half);
    s = d * d;
  }
  __syncthreads();
  stot[threadIdx.x] = s; __syncthreads();
  for (int st = 128; st > 0; st >>= 1) { if (threadIdx.x < st) stot[threadIdx.x] += stot[threadIdx.x + st]; __syncthreads(); }
  if (threadIdx.x == 0) atomicAdd(ifd_acc, stot[0]);
}

// ---------------- finalize ----------------
__global__ void finalize_kernel(const float* __restrict__ accs, float* __restrict__ out) {
  float l_main = accs[0];
  float scr0 = accs[1] * (1.0f / (32.0f * 64.0f * 128.0f * 128.0f));
  float scr1 = accs[2] * (1.0f / (32.0f * 128.0f * 64.0f * 64.0f));
  float l_scr = 0.5f * (scr0 + scr1);
  float ifd0 = accs[3] * (1.0f / (32.0f * 128.0f * 128.0f));
  float ifd1 = accs[4] * (1.0f / (32.0f * 64.0f * 64.0f));
  float ifd2 = accs[5] * (1.0f / (32.0f * 32.0f * 32.0f));
  float l_ifd = (ifd0 + ifd1 + ifd2) * (1.0f / 3.0f);
  float total = l_main + 0.015f * l_scr + 0.015f * l_ifd;
  out[0] = total; out[1] = l_main; out[2] = l_scr; out[3] = l_ifd;
}

extern "C" void kernel_launch(void* const* d_in, const int* in_sizes, int n_in,
                              void* d_out, int out_size, void* d_ws, size_t ws_size,
                              hipStream_t stream) {
  (void)in_sizes; (void)n_in; (void)out_size; (void)ws_size;
  const float* pred   = (const float*)d_in[0];
  const float* feat0  = (const float*)d_in[1];  // 32 x 64 x 128 x 128
  const float* feat1  = (const float*)d_in[2];  // 32 x 128 x 64 x 64
  const float* feat2  = (const float*)d_in[3];  // 32 x 256 x 32 x 32 (teacher)
  const int*   target = (const int*)d_in[4];
  float* out = (float*)d_out;

  float* ws   = (float*)d_ws;
  float* accs = ws;                      // 8 floats: [main, scr0, scr1, ifd0, ifd1, ifd2, -, -]
  int*   idx0 = (int*)(ws + 8);          // 64
  int*   idx1 = idx0 + 64;               // 128
  float* ns0  = (float*)(idx1 + 128);    // 32*64
  float* ns1  = ns0 + 32 * 64;           // 32*128
  float* ns2  = ns1 + 32 * 128;          // 32*256
  float* fl0  = ns2 + 32 * 256;          // 32*64
  float* fl1  = fl0 + 32 * 64;           // 32*128
  float* fl2  = fl1 + 32 * 128;          // 32*256

  perm_kernel<<<1, 256, 0, stream>>>(idx0, idx1, accs);
  main_loss_kernel<<<NB, 256, 0, stream>>>(pred, target, accs);

  pass1_kernel<64, 16384, 7, 2, true ><<<NB * 64, 256, 0, stream>>>(feat0, feat2, idx0, ns0, accs + 1);
  pass1_kernel<128, 4096, 6, 1, true ><<<NB * 128, 256, 0, stream>>>(feat1, feat2, idx1, ns1, accs + 2);
  pass1_kernel<256, 1024, 5, 0, false><<<NB * 256, 256, 0, stream>>>(feat2, nullptr, nullptr, ns2, nullptr);

  rank_kernel<64 ><<<NB, 256, 0, stream>>>(ns0, fl0);
  rank_kernel<128><<<NB, 256, 0, stream>>>(ns1, fl1);
  rank_kernel<256><<<NB, 256, 0, stream>>>(ns2, fl2);

  pass2_vec4<64, 16384><<<NB * 16, 256, 0, stream>>>(feat0, fl0, accs + 3, 1.0f / 32.0f);
  pass2_scalar<128, 4096><<<NB * 16, 256, 0, stream>>>(feat1, fl1, accs + 4, 1.0f / 64.0f);
  pass2_feat2<<<NB * 32, 256, 0, stream>>>(feat2, fl2, accs + 5);

  finalize_kernel<<<1, 1, 0, stream>>>(accs, out);
}

// Round 2
// 337.045 us; speedup vs baseline: 1.2632x; 1.2632x over previous
//
#include <hip/hip_runtime.h>
#include <stdint.h>
#include <math.h>

#define NB 32  // batch

// ---------------- Threefry-2x32-20 (exact JAX semantics) ----------------
__device__ __forceinline__ void tf_block(uint32_t k0, uint32_t k1, uint32_t& x0, uint32_t& x1) {
  uint32_t k2 = 0x1BD11BDAu ^ k0 ^ k1;
  x0 += k0; x1 += k1;
#define TFR(r) { x0 += x1; x1 = (x1 << r) | (x1 >> (32 - r)); x1 ^= x0; }
  TFR(13) TFR(15) TFR(26) TFR(6)
  x0 += k1; x1 += k2 + 1u;
  TFR(17) TFR(29) TFR(16) TFR(24)
  x0 += k2; x1 += k0 + 2u;
  TFR(13) TFR(15) TFR(26) TFR(6)
  x0 += k0; x1 += k1 + 3u;
  TFR(17) TFR(29) TFR(16) TFR(24)
  x0 += k1; x1 += k2 + 4u;
  TFR(13) TFR(15) TFR(26) TFR(6)
  x0 += k2; x1 += k0 + 5u;
#undef TFR
}

__device__ __forceinline__ float sigmoidf(float x) { return 1.0f / (1.0f + expf(-x)); }

// Block reduce (256 threads): wave shuffle + 4-slot LDS. Result valid on thread 0.
__device__ __forceinline__ float block_reduce(float v, float* red) {
  __syncthreads();  // protect red[] reuse across consecutive calls
  int lane = threadIdx.x & 63, wv = threadIdx.x >> 6;
  for (int o = 32; o > 0; o >>= 1) v += __shfl_down(v, o, 64);
  if (lane == 0) red[wv] = v;
  __syncthreads();
  float r = 0.f;
  if (threadIdx.x == 0) r = red[0] + red[1] + red[2] + red[3];
  return r;
}

// ---------------- K0: perms + zero the slot accumulators ----------------
// idx0[64], idx1[128] = jax.random.permutation(kt_i, 256)[:lim],
// kt_i from ks,kt = split(fold_in(key(42), i)).
__global__ __launch_bounds__(256) void k0_perm(int* idx0, int* idx1, float* ws) {
  __shared__ uint32_t sub[2][2];
  __shared__ uint32_t bits[2][256];
  int t = threadIdx.x;
  for (int i = t; i < 384; i += 256) ws[i] = 0.0f;  // slots + main acc
  if (t == 0) {
    for (int i = 0; i < 2; ++i) {
      uint32_t f0 = 0u, f1 = (uint32_t)i;          // fold_in(key(42), i)
      tf_block(0u, 42u, f0, f1);
      uint32_t a0 = 0u, a1 = 2u; tf_block(f0, f1, a0, a1);   // split -> kt = (e02.x1, e13.x1)
      uint32_t b0 = 1u, b1 = 3u; tf_block(f0, f1, b0, b1);
      uint32_t kt0 = a1, kt1 = b1;
      uint32_t c0 = 0u, c1 = 2u; tf_block(kt0, kt1, c0, c1); // split inside permutation
      uint32_t d0 = 1u, d1 = 3u; tf_block(kt0, kt1, d0, d1);
      sub[i][0] = c1; sub[i][1] = d1;
    }
  }
  __syncthreads();
  if (t < 128) {
    for (int i = 0; i < 2; ++i) {
      uint32_t x0 = (uint32_t)t, x1 = (uint32_t)(t + 128);
      tf_block(sub[i][0], sub[i][1], x0, x1);
      bits[i][t] = x0; bits[i][t + 128] = x1;
    }
  }
  __syncthreads();
  for (int i = 0; i < 2; ++i) {   // stable ascending rank = lax.sort_key_val
    uint32_t mine = bits[i][t];
    int rank = 0;
    for (int k = 0; k < 256; ++k) {
      uint32_t v = bits[i][k];
      rank += (v < mine) || (v == mine && k < t);
    }
    int lim = (i == 0) ? 64 : 128;
    if (rank < lim) { (i == 0 ? idx0 : idx1)[rank] = t; }
  }
}

// ---------------- K1: fused pass1 (plane ssq + SCR MSE) ----------------
template<int C, int HW, int LOGW, int SHIFT, bool STUDENT>
__device__ __forceinline__ void pass1_work(const float* __restrict__ feat,
                                           const float* __restrict__ teacher,
                                           const int* __restrict__ tidx,
                                           float* __restrict__ normsq,
                                           float* __restrict__ scr_slots,
                                           int bc, float* tpl, float* red) {
  if constexpr (STUDENT) {
    int b = bc / C, c = bc % C;
    int tc = tidx[c];
    ((float4*)tpl)[threadIdx.x] =
        ((const float4*)(teacher + ((size_t)b * 256 + tc) * 1024))[threadIdx.x];
    __syncthreads();
  }
  const float4* plane = (const float4*)(feat + (size_t)bc * HW);
  float ssq = 0.f, scr = 0.f;
  for (int p = threadIdx.x; p < HW / 4; p += 256) {
    float4 v = plane[p];
    ssq += v.x * v.x + v.y * v.y + v.z * v.z + v.w * v.w;
    if constexpr (STUDENT) {
      int pix = p * 4;
      int h = pix >> LOGW;
      int w = pix & ((1 << LOGW) - 1);
      int th = h >> SHIFT;
      if constexpr (SHIFT == 2) {
        float tv = tpl[th * 32 + (w >> 2)];
        float dx = v.x - tv, dy = v.y - tv, dz = v.z - tv, dw = v.w - tv;
        scr += dx * dx + dy * dy + dz * dz + dw * dw;
      } else {
        int tw = w >> 1;
        float t0 = tpl[th * 32 + tw], t1 = tpl[th * 32 + tw + 1];
        float dx = v.x - t0, dy = v.y - t0, dz = v.z - t1, dw = v.w - t1;
        scr += dx * dx + dy * dy + dz * dz + dw * dw;
      }
    }
  }
  float r = block_reduce(ssq, red);
  if (threadIdx.x == 0) normsq[bc] = r;
  if constexpr (STUDENT) {
    float r2 = block_reduce(scr, red);
    if (threadIdx.x == 0) atomicAdd(&scr_slots[bc & 63], r2);
  }
}

__global__ __launch_bounds__(256) void k1_pass1(
    const float* __restrict__ f0, const float* __restrict__ f1, const float* __restrict__ f2,
    const int* __restrict__ idx0, const int* __restrict__ idx1,
    float* __restrict__ ns0, float* __restrict__ ns1, float* __restrict__ ns2,
    float* __restrict__ scr0_s, float* __restrict__ scr1_s) {
  __shared__ float tpl[1024];
  __shared__ float red[8];
  int bid = blockIdx.x;
  if (bid < 2048)       pass1_work<64, 16384, 7, 2, true >(f0, f2, idx0, ns0, scr0_s, bid,        tpl, red);
  else if (bid < 6144)  pass1_work<128, 4096, 6, 1, true >(f1, f2, idx1, ns1, scr1_s, bid - 2048, tpl, red);
  else                  pass1_work<256, 1024, 5, 0, false>(f2, nullptr, nullptr, ns2, nullptr, bid - 6144, tpl, red);
}

// ---------------- K2: ranks (stable descending) + main loss ----------------
template<int C>
__device__ __forceinline__ void rank_work(const float* __restrict__ normsq,
                                          float* __restrict__ flags, int b, float* nm) {
  for (int c = threadIdx.x; c < C; c += 256) nm[c] = sqrtf(normsq[b * C + c]);
  __syncthreads();
  for (int c = threadIdx.x; c < C; c += 256) {
    float mine = nm[c];
    int rank = 0;
    for (int k = 0; k < C; ++k) {
      float v = nm[k];
      rank += (v > mine) || (v == mine && k < c);
    }
    flags[b * C + c] = (rank < C / 2) ? 1.0f : 0.0f;
  }
}

__device__ __forceinline__ void main_work(const float* __restrict__ pred,
                                          const int* __restrict__ target,
                                          float* acc, int b, float* sh) {
  int t = threadIdx.x;
  const float* row = pred + b * 1000;
  float m = -INFINITY;
  for (int j = t; j < 1000; j += 256) m = fmaxf(m, row[j]);
  sh[t] = m; __syncthreads();
  for (int s = 128; s > 0; s >>= 1) { if (t < s) sh[t] = fmaxf(sh[t], sh[t + s]); __syncthreads(); }
  m = sh[0]; __syncthreads();
  float e = 0.f;
  for (int j = t; j < 1000; j += 256) e += expf(row[j] - m);
  sh[t] = e; __syncthreads();
  for (int s = 128; s > 0; s >>= 1) { if (t < s) sh[t] += sh[t + s]; __syncthreads(); }
  if (t == 0) atomicAdd(acc, (logf(sh[0]) + m - row[target[b]]) * (1.0f / 32.0f));
}

__global__ __launch_bounds__(256) void k2_rank_main(
    const float* __restrict__ ns0, const float* __restrict__ ns1, const float* __restrict__ ns2,
    float* __restrict__ fl0, float* __restrict__ fl1, float* __restrict__ fl2,
    const float* __restrict__ pred, const int* __restrict__ target, float* main_acc) {
  __shared__ float sh[256];
  int bid = blockIdx.x;
  if (bid < 32)       rank_work<64 >(ns0, fl0, bid,      sh);
  else if (bid < 64)  rank_work<128>(ns1, fl1, bid - 32, sh);
  else if (bid < 96)  rank_work<256>(ns2, fl2, bid - 64, sh);
  else                main_work(pred, target, main_acc, bid - 96, sh);
}

// ---------------- K3: fused pass2 (IFD) ----------------
template<int C, int HW>
__device__ __forceinline__ void pass2_vec4_work(const float* __restrict__ feat,
                                                const float* __restrict__ flags,
                                                float* __restrict__ slots, float inv_half,
                                                int bid, float* fl, float* red) {
  const int nchunk = HW / 1024;
  int b = bid / nchunk, chunk = bid % nchunk;
  for (int c = threadIdx.x; c < C; c += 256) fl[c] = flags[b * C + c];
  __syncthreads();
  const float* base = feat + (size_t)b * C * HW + (size_t)chunk * 1024;
  float4 tot = {0, 0, 0, 0}, str = {0, 0, 0, 0};
  for (int c = 0; c < C; ++c) {
    float4 v = ((const float4*)(base + (size_t)c * HW))[threadIdx.x];
    float f = fl[c];
    tot.x += v.x; tot.y += v.y; tot.z += v.z; tot.w += v.w;
    str.x = fmaf(v.x, f, str.x); str.y = fmaf(v.y, f, str.y);
    str.z = fmaf(v.z, f, str.z); str.w = fmaf(v.w, f, str.w);
  }
  float s = 0.f, d;
  d = sigmoidf((tot.x - str.x) * inv_half) - sigmoidf(str.x * inv_half); s += d * d;
  d = sigmoidf((tot.y - str.y) * inv_half) - sigmoidf(str.y * inv_half); s += d * d;
  d = sigmoidf((tot.z - str.z) * inv_half) - sigmoidf(str.z * inv_half); s += d * d;
  d = sigmoidf((tot.w - str.w) * inv_half) - sigmoidf(str.w * inv_half); s += d * d;
  float r = block_reduce(s, red);
  if (threadIdx.x == 0) atomicAdd(&slots[bid & 63], r);
}

__device__ __forceinline__ void pass2_feat2_work(const float* __restrict__ feat,
                                                 const float* __restrict__ flags,
                                                 float* __restrict__ slots, int bid,
                                                 float* fl, float* stot, float* sstr, float* red) {
  int b = bid >> 5, h = bid & 31;
  fl[threadIdx.x] = flags[b * 256 + threadIdx.x];
  __syncthreads();
  int w = threadIdx.x & 31;
  int cl = threadIdx.x >> 5;  // 0..7
  const float* base = feat + (size_t)b * 256 * 1024 + h * 32 + w;
  float tot = 0.f, str = 0.f;
  for (int cg = 0; cg < 32; ++cg) {
    int c = cg * 8 + cl;
    float v = base[(size_t)c * 1024];
    tot += v; str = fmaf(v, fl[c], str);
  }
  stot[threadIdx.x] = tot; sstr[threadIdx.x] = str;
  __syncthreads();
  float s = 0.f;
  if (threadIdx.x < 32) {
    float T = 0.f, S = 0.f;
    for (int k = 0; k < 8; ++k) { T += stot[k * 32 + threadIdx.x]; S += sstr[k * 32 + threadIdx.x]; }
    const float ih = 1.0f / 128.0f;
    float d = sigmoidf((T - S) * ih) - sigmoidf(S * ih);
    s = d * d;
  }
  float r = block_reduce(s, red);
  if (threadIdx.x == 0) atomicAdd(&slots[bid & 63], r);
}

__global__ __launch_bounds__(256) void k3_pass2(
    const float* __restrict__ f0, const float* __restrict__ f1, const float* __restrict__ f2,
    const float* __restrict__ fl0, const float* __restrict__ fl1, const float* __restrict__ fl2,
    float* __restrict__ ifd0_s, float* __restrict__ ifd1_s, float* __restrict__ ifd2_s) {
  __shared__ float fl[256];
  __shared__ float s1[256];
  __shared__ float s2[256];
  __shared__ float red[8];
  int bid = blockIdx.x;
  if (bid < 512)      pass2_vec4_work<64, 16384>(f0, fl0, ifd0_s, 1.0f / 32.0f, bid, fl, red);
  else if (bid < 640) pass2_vec4_work<128, 4096>(f1, fl1, ifd1_s, 1.0f / 64.0f, bid - 512, fl, red);
  else                pass2_feat2_work(f2, fl2, ifd2_s, bid - 640, fl, s1, s2, red);
}

// ---------------- K4: finalize ----------------
__global__ void k4_finalize(const float* __restrict__ ws, float* __restrict__ out) {
  float scr0 = 0.f, scr1 = 0.f, ifd0 = 0.f, ifd1 = 0.f, ifd2 = 0.f;
  for (int i = 0; i < 64; ++i) {
    scr0 += ws[i];       scr1 += ws[64 + i];
    ifd0 += ws[128 + i]; ifd1 += ws[192 + i]; ifd2 += ws[256 + i];
  }
  float l_main = ws[320];
  scr0 *= (1.0f / (32.0f * 64.0f * 128.0f * 128.0f));
  scr1 *= (1.0f / (32.0f * 128.0f * 64.0f * 64.0f));
  float l_scr = 0.5f * (scr0 + scr1);
  ifd0 *= (1.0f / (32.0f * 128.0f * 128.0f));
  ifd1 *= (1.0f / (32.0f * 64.0f * 64.0f));
  ifd2 *= (1.0f / (32.0f * 32.0f * 32.0f));
  float l_ifd = (ifd0 + ifd1 + ifd2) * (1.0f / 3.0f);
  float total = l_main + 0.015f * l_scr + 0.015f * l_ifd;
  out[0] = total; out[1] = l_main; out[2] = l_scr; out[3] = l_ifd;
}

extern "C" void kernel_launch(void* const* d_in, const int* in_sizes, int n_in,
                              void* d_out, int out_size, void* d_ws, size_t ws_size,
                              hipStream_t stream) {
  (void)in_sizes; (void)n_in; (void)out_size; (void)ws_size;
  const float* pred   = (const float*)d_in[0];
  const float* feat0  = (const float*)d_in[1];  // 32 x 64 x 128 x 128
  const float* feat1  = (const float*)d_in[2];  // 32 x 128 x 64 x 64
  const float* feat2  = (const float*)d_in[3];  // 32 x 256 x 32 x 32 (teacher)
  const int*   target = (const int*)d_in[4];
  float* out = (float*)d_out;

  // ws layout (floats):
  // [0,64)=scr0 slots [64,128)=scr1 [128,192)=ifd0 [192,256)=ifd1 [256,320)=ifd2 [320]=main
  float* ws = (float*)d_ws;
  float* scr0_s = ws;
  float* scr1_s = ws + 64;
  float* ifd0_s = ws + 128;
  float* ifd1_s = ws + 192;
  float* ifd2_s = ws + 256;
  float* main_a = ws + 320;
  int*   idx0 = (int*)(ws + 384);        // 64
  int*   idx1 = idx0 + 64;               // 128
  float* ns0  = (float*)(idx1 + 128);    // 32*64
  float* ns1  = ns0 + 2048;              // 32*128
  float* ns2  = ns1 + 4096;              // 32*256
  float* fl0  = ns2 + 8192;
  float* fl1  = fl0 + 2048;
  float* fl2  = fl1 + 4096;

  k0_perm<<<1, 256, 0, stream>>>(idx0, idx1, ws);
  k1_pass1<<<14336, 256, 0, stream>>>(feat0, feat1, feat2, idx0, idx1, ns0, ns1, ns2, scr0_s, scr1_s);
  k2_rank_main<<<128, 256, 0, stream>>>(ns0, ns1, ns2, fl0, fl1, fl2, pred, target, main_a);
  k3_pass2<<<1664, 256, 0, stream>>>(feat0, feat1, feat2, fl0, fl1, fl2, ifd0_s, ifd1_s, ifd2_s);
  k4_finalize<<<1, 1, 0, stream>>>(ws, out);
}